// Round 3
// baseline (1460.289 us; speedup 1.0000x reference)
//
#include <hip/hip_runtime.h>
#include <stdint.h>

#define NN 50000
#define NE 1600000
#define BE 128

typedef __attribute__((ext_vector_type(8))) short short8;
typedef __attribute__((ext_vector_type(4))) float f32x4;

__device__ __forceinline__ unsigned short f2bf(float f) {
    unsigned int u = __float_as_uint(f);
    u += 0x7fff + ((u >> 16) & 1);   // round-nearest-even
    return (unsigned short)(u >> 16);
}

__device__ __forceinline__ float silu_f(float v) {
    return v / (1.0f + __expf(-v));
}

// ws layout:
// bytes [0, 98304)          : bf16 weights (ushort)
//   [0,20480)      node_w1^T  [128][160]
//   [20480,40960)  coord_w1^T [128][160]
//   [40960,49152)  node_w2^T  [64][128]
// bytes [98304, 299008)     : hist/offs (int[50176])   -- sort scratch
// bytes [299008, 6699008)   : perm (int[NE])           -- dst-sorted edge ids
#define WS_HIST_B 98304
#define WS_PERM_B 299008
#define WS_NEED_B 6699008

__global__ void prep_kernel(const float* __restrict__ nw1,
                            const float* __restrict__ cw1,
                            const float* __restrict__ nw2,
                            unsigned short* __restrict__ ws) {
    int i = blockIdx.x * 256 + threadIdx.x;
    if (i < 20480) {
        int n = i / 160, k = i % 160;
        ws[i] = f2bf(nw1[k * 128 + n]);
    } else if (i < 40960) {
        int j = i - 20480; int n = j / 160, k = j % 160;
        ws[i] = f2bf(cw1[k * 128 + n]);
    } else if (i < 49152) {
        int j = i - 40960; int o = j / 128, k = j % 128;
        ws[i] = f2bf(nw2[k * 64 + o]);
    }
}

// out[0:3.2M] = h, out[3.2M:3.35M] = x   (both div by 4)
__global__ void init_out(const float4* __restrict__ h4,
                         const float4* __restrict__ x4,
                         float4* __restrict__ out4) {
    int i = blockIdx.x * 256 + threadIdx.x;
    if (i < 800000)       out4[i] = h4[i];
    else if (i < 837500)  out4[i] = x4[i - 800000];
}

// ---------------- counting-sort of edges by dst ----------------
__global__ void zero_hist(int* __restrict__ hist) {
    int i = blockIdx.x * 256 + threadIdx.x;
    if (i < NN) hist[i] = 0;
}

__global__ void hist_kernel(const int* __restrict__ eidx, int* __restrict__ hist) {
    int e = blockIdx.x * 256 + threadIdx.x;
    if (e < NE) atomicAdd(&hist[eidx[NE + e]], 1);
}

// single-block exclusive scan over NN counters (in place: hist -> offsets)
__global__ __launch_bounds__(1024)
void scan_kernel(int* __restrict__ hist) {
    __shared__ int tmp[1024];
    __shared__ int carry;
    const int tid = threadIdx.x;
    if (tid == 0) carry = 0;
    __syncthreads();
    for (int base = 0; base < NN; base += 1024) {
        int v = (base + tid < NN) ? hist[base + tid] : 0;
        tmp[tid] = v;
        __syncthreads();
        #pragma unroll
        for (int off = 1; off < 1024; off <<= 1) {
            int t = (tid >= off) ? tmp[tid - off] : 0;
            __syncthreads();
            tmp[tid] += t;
            __syncthreads();
        }
        int excl = carry + tmp[tid] - v;
        if (base + tid < NN) hist[base + tid] = excl;
        __syncthreads();                 // all reads of carry done
        if (tid == 1023) carry += tmp[1023];
        __syncthreads();                 // carry update visible, tmp reusable
    }
}

// offs used destructively as per-bin cursors; perm becomes dst-sorted edge ids
__global__ void scatter_kernel(const int* __restrict__ eidx,
                               int* __restrict__ offs,
                               int* __restrict__ perm) {
    int e = blockIdx.x * 256 + threadIdx.x;
    if (e < NE) {
        int d = eidx[NE + e];
        int p = atomicAdd(&offs[d], 1);
        perm[p] = e;
    }
}

#define MIS 168   // m_input row stride (ushorts); 336B = 21*16B -> aligned + 2-way-free banks

__global__ __launch_bounds__(256, 3)
void egnn_edge_kernel(const float* __restrict__ h,
                      const float* __restrict__ x,
                      const int* __restrict__ eidx,
                      const float* __restrict__ edist,
                      const float* __restrict__ node_b1,
                      const float* __restrict__ node_b2,
                      const float* __restrict__ coord_b1,
                      const float* __restrict__ coord_w2,
                      const float* __restrict__ ew1,
                      const float* __restrict__ eb1,
                      const float* __restrict__ ew2,
                      const float* __restrict__ eb2,
                      const unsigned short* __restrict__ ws,
                      const int* __restrict__ perm,
                      float* __restrict__ out_h,
                      float* __restrict__ out_x) {
    // LDS: 128*168*2 + small = ~44.5 KB -> 3 blocks/CU (12 waves/CU)
    __shared__ unsigned short mi[BE * MIS];  // m_input tile -> hidden tile -> fp32 m rows
    __shared__ int peS[BE];                  // permuted edge ids for this block
    __shared__ int dstS[BE];                 // dst node per row (sorted within block)
    __shared__ int headsS[BE];
    __shared__ int nheads;

    const int tid  = threadIdx.x;
    const int w    = tid >> 6;      // wave 0..3, owns edge rows [w*32, w*32+32)
    const int lane = tid & 63;
    const int ln   = lane & 15;
    const int quad = lane >> 4;
    const int e0   = blockIdx.x * BE;

    if (tid < BE) peS[tid] = perm ? perm[e0 + tid] : (e0 + tid);
    if (tid == 0) nheads = 0;
    __syncthreads();
    if (tid < BE) dstS[tid] = eidx[NE + peS[tid]];

    // ---- stage m_input cols 0..127: gather h[src], h[dst] as bf16 ----
    {
        const float4* h4 = (const float4*)h;
        const int g = tid >> 4, l16 = tid & 15;
        #pragma unroll
        for (int it = 0; it < 16; ++it) {
            int row = it * 16 + g;                 // 0..255: 0..127 src, 128..255 dst
            int e = row & 127;
            int pe = peS[e];
            int node = (row < 128) ? eidx[pe] : eidx[NE + pe];
            int cbase = (row < 128) ? 0 : 64;
            float4 v = h4[node * 16 + l16];
            unsigned short b[4] = {f2bf(v.x), f2bf(v.y), f2bf(v.z), f2bf(v.w)};
            *(uint2*)&mi[e * MIS + cbase + l16 * 4] = *(uint2*)b;
        }
    }
    // ---- stage m_input cols 128..159: edge MLP (fp32) ----
    {
        int e = tid >> 1, half = tid & 1;
        float d = edist[peS[e]];
        float s[16];
        #pragma unroll
        for (int jj = 0; jj < 16; ++jj) s[jj] = eb2[half * 16 + jj];
        #pragma unroll
        for (int k = 0; k < 32; ++k) {
            float tk = silu_f(d * ew1[k] + eb1[k]);
            const float* r2 = ew2 + k * 32 + half * 16;
            #pragma unroll
            for (int jj = 0; jj < 16; ++jj) s[jj] += tk * r2[jj];
        }
        unsigned short sb[16];
        #pragma unroll
        for (int jj = 0; jj < 16; ++jj) sb[jj] = f2bf(s[jj]);
        *(uint4*)&mi[e * MIS + 128 + half * 16]     = *(uint4*)&sb[0];
        *(uint4*)&mi[e * MIS + 128 + half * 16 + 8] = *(uint4*)&sb[8];
    }

    __syncthreads();   // staging complete (incl. dstS)

    const int arow0 = (w * 32 + ln) * MIS;
    const int arow1 = (w * 32 + 16 + ln) * MIS;
    const int koff  = quad * 8;
    const f32x4 zero = {0.f, 0.f, 0.f, 0.f};

    // ---- A fragments: load once, reuse for both GEMM1 phases ----
    short8 aA[5], aB[5];
    #pragma unroll
    for (int kc = 0; kc < 5; ++kc) {
        aA[kc] = *(const short8*)&mi[arow0 + kc * 32 + koff];
        aB[kc] = *(const short8*)&mi[arow1 + kc * 32 + koff];
    }

    const int wvoff = ln * 160 + koff;   // per-lane B-row offset (ushorts)

    // ---- GEMM1-coord: [128,160] @ [160,128], B straight from global (L1/L2-hot) ----
    f32x4 accC[2][8];
    #pragma unroll
    for (int a = 0; a < 2; ++a)
        #pragma unroll
        for (int b = 0; b < 8; ++b) accC[a][b] = zero;
    {
        const unsigned short* wsrc = ws + 20480;   // coord_w1^T
        #pragma unroll
        for (int half = 0; half < 2; ++half) {
            #pragma unroll
            for (int kc = 0; kc < 5; ++kc) {
                #pragma unroll
                for (int nt = 0; nt < 4; ++nt) {
                    short8 b = *(const short8*)(wsrc + half * 10240 + nt * 2560
                                                + kc * 32 + wvoff);
                    const int nn = half * 4 + nt;
                    accC[0][nn] = __builtin_amdgcn_mfma_f32_16x16x32_bf16(aA[kc], b, accC[0][nn], 0, 0, 0);
                    accC[1][nn] = __builtin_amdgcn_mfma_f32_16x16x32_bf16(aB[kc], b, accC[1][nn], 0, 0, 0);
                }
            }
        }
    }

    // ---- coord epilogue: cw[e] = silu(accC + b1c) . w2c, then x scatter ----
    {
        float cw[2][4];
        #pragma unroll
        for (int mt = 0; mt < 2; ++mt)
            #pragma unroll
            for (int r = 0; r < 4; ++r) cw[mt][r] = 0.f;
        #pragma unroll
        for (int nt = 0; nt < 8; ++nt) {
            int col = nt * 16 + ln;
            float b1v = coord_b1[col];
            float w2v = coord_w2[col];
            #pragma unroll
            for (int mt = 0; mt < 2; ++mt)
                #pragma unroll
                for (int r = 0; r < 4; ++r)
                    cw[mt][r] += silu_f(accC[mt][nt][r] + b1v) * w2v;
        }
        #pragma unroll
        for (int off = 1; off < 16; off <<= 1) {
            #pragma unroll
            for (int mt = 0; mt < 2; ++mt)
                #pragma unroll
                for (int r = 0; r < 4; ++r)
                    cw[mt][r] += __shfl_xor(cw[mt][r], off, 64);
        }
        // lanes ln<8 per quad each handle one (mt,r) edge
        if (ln < 8) {
            const int smt = ln >> 2, sr = ln & 3;
            float cwsel = 0.f;
            #pragma unroll
            for (int mt = 0; mt < 2; ++mt)
                #pragma unroll
                for (int r = 0; r < 4; ++r)
                    cwsel = (mt == smt && r == sr) ? cw[mt][r] : cwsel;
            int lrow = w * 32 + smt * 16 + quad * 4 + sr;
            int s = eidx[peS[lrow]], dn = dstS[lrow];
            float dx = x[s * 3]     - x[dn * 3];
            float dy = x[s * 3 + 1] - x[dn * 3 + 1];
            float dz = x[s * 3 + 2] - x[dn * 3 + 2];
            float len = fmaxf(sqrtf(dx * dx + dy * dy + dz * dz), 1e-8f);
            float k = cwsel / len;
            atomicAdd(out_x + dn * 3,     k * dx);
            atomicAdd(out_x + dn * 3 + 1, k * dy);
            atomicAdd(out_x + dn * 3 + 2, k * dz);
        }
    }

    // ---- GEMM1-node ----
    f32x4 accN[2][8];
    #pragma unroll
    for (int a = 0; a < 2; ++a)
        #pragma unroll
        for (int b = 0; b < 8; ++b) accN[a][b] = zero;
    {
        const unsigned short* wsrc = ws;           // node_w1^T
        #pragma unroll
        for (int half = 0; half < 2; ++half) {
            #pragma unroll
            for (int kc = 0; kc < 5; ++kc) {
                #pragma unroll
                for (int nt = 0; nt < 4; ++nt) {
                    short8 b = *(const short8*)(wsrc + half * 10240 + nt * 2560
                                                + kc * 32 + wvoff);
                    const int nn = half * 4 + nt;
                    accN[0][nn] = __builtin_amdgcn_mfma_f32_16x16x32_bf16(aA[kc], b, accN[0][nn], 0, 0, 0);
                    accN[1][nn] = __builtin_amdgcn_mfma_f32_16x16x32_bf16(aB[kc], b, accN[1][nn], 0, 0, 0);
                }
            }
        }
    }

    // ---- hidden = silu(accN + b1) -> bf16, overwrite OWN rows of mi ----
    #pragma unroll
    for (int mt = 0; mt < 2; ++mt) {
        const int rowb = (w * 32 + mt * 16 + quad * 4) * MIS;
        #pragma unroll
        for (int nt = 0; nt < 8; ++nt) {
            int col = nt * 16 + ln;
            float b1v = node_b1[col];
            #pragma unroll
            for (int r = 0; r < 4; ++r)
                mi[rowb + r * MIS + col] = f2bf(silu_f(accN[mt][nt][r] + b1v));
        }
    }

    // ---- GEMM2-node: [128,128] @ [128,64] ----
    f32x4 acc2[2][4];
    #pragma unroll
    for (int a = 0; a < 2; ++a)
        #pragma unroll
        for (int b = 0; b < 4; ++b) acc2[a][b] = zero;
    const unsigned short* nw2T = ws + 40960;
    #pragma unroll
    for (int kc = 0; kc < 4; ++kc) {
        short8 a0 = *(const short8*)&mi[arow0 + kc * 32 + koff];
        short8 a1 = *(const short8*)&mi[arow1 + kc * 32 + koff];
        #pragma unroll
        for (int nt = 0; nt < 4; ++nt) {
            short8 b = *(const short8*)(nw2T + (nt * 16 + ln) * 128 + kc * 32 + koff);
            acc2[0][nt] = __builtin_amdgcn_mfma_f32_16x16x32_bf16(a0, b, acc2[0][nt], 0, 0, 0);
            acc2[1][nt] = __builtin_amdgcn_mfma_f32_16x16x32_bf16(a1, b, acc2[1][nt], 0, 0, 0);
        }
    }

    // ---- node scatter, dst-grouped: m+b2 rows -> LDS fp32, one atomic per run ----
    __syncthreads();           // all mi (GEMM2 A) reads done before fp32 overwrite
    float* macc = (float*)mi;  // [128][64] fp32 = 32 KB
    #pragma unroll
    for (int mt = 0; mt < 2; ++mt) {
        #pragma unroll
        for (int r = 0; r < 4; ++r) {
            int lrow = w * 32 + mt * 16 + quad * 4 + r;
            #pragma unroll
            for (int nt = 0; nt < 4; ++nt) {
                int col = nt * 16 + ln;
                macc[lrow * 64 + col] = acc2[mt][nt][r] + node_b2[col];
            }
        }
    }
    __syncthreads();           // macc + nheads(=0) ready
    if (tid < BE) {
        bool isHead = (tid == 0) || (dstS[tid] != dstS[tid - 1]);
        if (isHead) { int k = atomicAdd(&nheads, 1); headsS[k] = tid; }
    }
    __syncthreads();
    {
        const int nh = nheads;
        for (int k = w; k < nh; k += 4) {      // wave w takes every 4th run
            int i = headsS[k];
            int d = dstS[i];
            int jend = i + 1;
            while (jend < BE && dstS[jend] == d) ++jend;
            float sum = 0.f;
            for (int r = i; r < jend; ++r) sum += macc[r * 64 + lane];
            atomicAdd(out_h + (size_t)d * 64 + lane, sum);
        }
    }
}

extern "C" void kernel_launch(void* const* d_in, const int* in_sizes, int n_in,
                              void* d_out, int out_size, void* d_ws, size_t ws_size,
                              hipStream_t stream) {
    const float* h    = (const float*)d_in[0];
    const float* x    = (const float*)d_in[1];
    const int*   eidx = (const int*)d_in[2];
    const float* edist= (const float*)d_in[3];
    const float* nw1  = (const float*)d_in[4];
    const float* nb1  = (const float*)d_in[5];
    const float* nw2  = (const float*)d_in[6];
    const float* nb2  = (const float*)d_in[7];
    const float* cw1  = (const float*)d_in[8];
    const float* cb1  = (const float*)d_in[9];
    const float* cw2  = (const float*)d_in[10];
    const float* ew1  = (const float*)d_in[11];
    const float* eb1  = (const float*)d_in[12];
    const float* ew2  = (const float*)d_in[13];
    const float* eb2  = (const float*)d_in[14];
    float* out = (float*)d_out;
    unsigned short* ws = (unsigned short*)d_ws;

    prep_kernel<<<192, 256, 0, stream>>>(nw1, cw1, nw2, ws);
    init_out<<<3272, 256, 0, stream>>>((const float4*)h, (const float4*)x, (float4*)out);

    const int* perm = nullptr;
    if (ws_size >= (size_t)WS_NEED_B) {
        int* hist  = (int*)((char*)d_ws + WS_HIST_B);
        int* permw = (int*)((char*)d_ws + WS_PERM_B);
        zero_hist<<<196, 256, 0, stream>>>(hist);
        hist_kernel<<<NE / 256, 256, 0, stream>>>(eidx, hist);
        scan_kernel<<<1, 1024, 0, stream>>>(hist);
        scatter_kernel<<<NE / 256, 256, 0, stream>>>(eidx, hist, permw);
        perm = permw;
    }

    egnn_edge_kernel<<<NE / BE, 256, 0, stream>>>(h, x, eidx, edist,
                                                  nb1, nb2, cb1, cw2,
                                                  ew1, eb1, ew2, eb2,
                                                  ws, perm, out, out + 3200000);
}

// Round 4
// 828.595 us; speedup vs baseline: 1.7624x; 1.7624x over previous
//
#include <hip/hip_runtime.h>
#include <hip/hip_bf16.h>
#include <stdint.h>

#define NN 50000
#define NE 1600000
#define BE 128

typedef __attribute__((ext_vector_type(8))) short short8;
typedef __attribute__((ext_vector_type(4))) float f32x4;

__device__ __forceinline__ unsigned short f2bf(float f) {
    unsigned int u = __float_as_uint(f);
    u += 0x7fff + ((u >> 16) & 1);   // round-nearest-even
    return (unsigned short)(u >> 16);
}

// packed 2x f32 -> 2x bf16 (v_cvt_pk_bf16_f32 on gfx950)
__device__ __forceinline__ unsigned int pk2bf(float lo, float hi) {
    __hip_bfloat162 b = __float22bfloat162_rn(float2{lo, hi});
    return *(unsigned int*)&b;
}

// silu via fast rcp (v_rcp_f32, ~1ulp) instead of precise divide (~8 VALU ops)
__device__ __forceinline__ float silu_f(float v) {
    return v * __builtin_amdgcn_rcpf(1.0f + __expf(-v));
}

// ws layout (ushort):
// [0,20480)      node_w1^T  [128][160]
// [20480,40960)  coord_w1^T [128][160]
// [40960,49152)  node_w2^T  [64][128]
__global__ void prep_kernel(const float* __restrict__ nw1,
                            const float* __restrict__ cw1,
                            const float* __restrict__ nw2,
                            unsigned short* __restrict__ ws) {
    int i = blockIdx.x * 256 + threadIdx.x;
    if (i < 20480) {
        int n = i / 160, k = i % 160;
        ws[i] = f2bf(nw1[k * 128 + n]);
    } else if (i < 40960) {
        int j = i - 20480; int n = j / 160, k = j % 160;
        ws[i] = f2bf(cw1[k * 128 + n]);
    } else if (i < 49152) {
        int j = i - 40960; int o = j / 128, k = j % 128;
        ws[i] = f2bf(nw2[k * 64 + o]);
    }
}

// out[0:3.2M] = h, out[3.2M:3.35M] = x   (both div by 4)
__global__ void init_out(const float4* __restrict__ h4,
                         const float4* __restrict__ x4,
                         float4* __restrict__ out4) {
    int i = blockIdx.x * 256 + threadIdx.x;
    if (i < 800000)       out4[i] = h4[i];
    else if (i < 837500)  out4[i] = x4[i - 800000];
}

#define MIS 168   // m_input row stride (ushorts); 336B = 21*16B -> aligned + 2-way-free banks

__global__ __launch_bounds__(256, 3)
void egnn_edge_kernel(const float* __restrict__ h,
                      const float* __restrict__ x,
                      const int* __restrict__ eidx,
                      const float* __restrict__ edist,
                      const float* __restrict__ node_b1,
                      const float* __restrict__ node_b2,
                      const float* __restrict__ coord_b1,
                      const float* __restrict__ coord_w2,
                      const float* __restrict__ ew1,
                      const float* __restrict__ eb1,
                      const float* __restrict__ ew2,
                      const float* __restrict__ eb2,
                      const unsigned short* __restrict__ ws,
                      float* __restrict__ out_h,
                      float* __restrict__ out_x) {
    // LDS: 128*168*2 + 1KB = 44032 B -> 3 blocks/CU (12 waves/CU)
    __shared__ unsigned short mi[BE * MIS];     // m_input tile, later hidden tile
    __shared__ int srcS[BE];                    // src node ids (block-preloaded)
    __shared__ int dstS[BE];                    // dst node ids

    const int tid  = threadIdx.x;
    const int w    = tid >> 6;      // wave 0..3, owns edge rows [w*32, w*32+32)
    const int lane = tid & 63;
    const int ln   = lane & 15;
    const int quad = lane >> 4;
    const int e0   = blockIdx.x * BE;

    // ---- preload edge indices once (coalesced), kill 16 scattered reads/thread ----
    if (tid < BE)      srcS[tid]       = eidx[e0 + tid];
    else               dstS[tid - BE]  = eidx[NE + e0 + tid - BE];
    __syncthreads();

    // ---- stage m_input cols 0..127: gather h[src], h[dst] as bf16 ----
    {
        const float4* h4 = (const float4*)h;
        const int g = tid >> 4, l16 = tid & 15;
        #pragma unroll
        for (int it = 0; it < 16; ++it) {
            int row = it * 16 + g;                 // 0..255: 0..127 src, 128..255 dst
            int e = row & 127;
            int node = (row < 128) ? srcS[e] : dstS[e];
            int cbase = (row < 128) ? 0 : 64;
            float4 v = h4[node * 16 + l16];
            uint2 u;
            u.x = pk2bf(v.x, v.y);
            u.y = pk2bf(v.z, v.w);
            *(uint2*)&mi[e * MIS + cbase + l16 * 4] = u;
        }
    }
    // ---- stage m_input cols 128..159: edge MLP (fp32) ----
    {
        int e = tid >> 1, half = tid & 1;
        float d = edist[e0 + e];
        float s[16];
        #pragma unroll
        for (int jj = 0; jj < 16; ++jj) s[jj] = eb2[half * 16 + jj];
        #pragma unroll
        for (int k = 0; k < 32; ++k) {
            float tk = silu_f(d * ew1[k] + eb1[k]);
            const float* r2 = ew2 + k * 32 + half * 16;
            #pragma unroll
            for (int jj = 0; jj < 16; ++jj) s[jj] += tk * r2[jj];
        }
        uint4 u0, u1;
        u0.x = pk2bf(s[0], s[1]);  u0.y = pk2bf(s[2], s[3]);
        u0.z = pk2bf(s[4], s[5]);  u0.w = pk2bf(s[6], s[7]);
        u1.x = pk2bf(s[8], s[9]);  u1.y = pk2bf(s[10], s[11]);
        u1.z = pk2bf(s[12], s[13]); u1.w = pk2bf(s[14], s[15]);
        *(uint4*)&mi[e * MIS + 128 + half * 16]     = u0;
        *(uint4*)&mi[e * MIS + 128 + half * 16 + 8] = u1;
    }

    __syncthreads();   // staging complete; from here each wave touches only its own rows

    const int arow0 = (w * 32 + ln) * MIS;
    const int arow1 = (w * 32 + 16 + ln) * MIS;
    const int koff  = quad * 8;
    const f32x4 zero = {0.f, 0.f, 0.f, 0.f};

    // ---- A fragments: load once, reuse for both GEMM1 phases (10 ds_read_b128) ----
    short8 aA[5], aB[5];
    #pragma unroll
    for (int kc = 0; kc < 5; ++kc) {
        aA[kc] = *(const short8*)&mi[arow0 + kc * 32 + koff];
        aB[kc] = *(const short8*)&mi[arow1 + kc * 32 + koff];
    }

    const int wvoff = ln * 160 + koff;   // per-lane B-row offset (ushorts)

    // ---- GEMM1-coord: [128,160] @ [160,128], B straight from global (L1/L2-hot) ----
    f32x4 accC[2][8];
    #pragma unroll
    for (int a = 0; a < 2; ++a)
        #pragma unroll
        for (int b = 0; b < 8; ++b) accC[a][b] = zero;
    {
        const unsigned short* wsrc = ws + 20480;   // coord_w1^T
        #pragma unroll
        for (int half = 0; half < 2; ++half) {
            #pragma unroll
            for (int kc = 0; kc < 5; ++kc) {
                #pragma unroll
                for (int nt = 0; nt < 4; ++nt) {
                    short8 b = *(const short8*)(wsrc + half * 10240 + nt * 2560
                                                + kc * 32 + wvoff);
                    const int nn = half * 4 + nt;
                    accC[0][nn] = __builtin_amdgcn_mfma_f32_16x16x32_bf16(aA[kc], b, accC[0][nn], 0, 0, 0);
                    accC[1][nn] = __builtin_amdgcn_mfma_f32_16x16x32_bf16(aB[kc], b, accC[1][nn], 0, 0, 0);
                }
            }
        }
    }

    // ---- coord epilogue: cw[e] = silu(accC + b1c) . w2c, then x scatter ----
    {
        float cw[2][4];
        #pragma unroll
        for (int mt = 0; mt < 2; ++mt)
            #pragma unroll
            for (int r = 0; r < 4; ++r) cw[mt][r] = 0.f;
        #pragma unroll
        for (int nt = 0; nt < 8; ++nt) {
            int col = nt * 16 + ln;
            float b1v = coord_b1[col];
            float w2v = coord_w2[col];
            #pragma unroll
            for (int mt = 0; mt < 2; ++mt)
                #pragma unroll
                for (int r = 0; r < 4; ++r)
                    cw[mt][r] += silu_f(accC[mt][nt][r] + b1v) * w2v;
        }
        #pragma unroll
        for (int off = 1; off < 16; off <<= 1) {
            #pragma unroll
            for (int mt = 0; mt < 2; ++mt)
                #pragma unroll
                for (int r = 0; r < 4; ++r)
                    cw[mt][r] += __shfl_xor(cw[mt][r], off, 64);
        }
        // lanes ln<8 per quad each handle one (mt,r) edge
        if (ln < 8) {
            const int smt = ln >> 2, sr = ln & 3;
            float cwsel = 0.f;
            #pragma unroll
            for (int mt = 0; mt < 2; ++mt)
                #pragma unroll
                for (int r = 0; r < 4; ++r)
                    cwsel = (mt == smt && r == sr) ? cw[mt][r] : cwsel;
            int lrow = w * 32 + smt * 16 + quad * 4 + sr;
            int s = srcS[lrow], dn = dstS[lrow];
            float dx = x[s * 3]     - x[dn * 3];
            float dy = x[s * 3 + 1] - x[dn * 3 + 1];
            float dz = x[s * 3 + 2] - x[dn * 3 + 2];
            float len = fmaxf(sqrtf(dx * dx + dy * dy + dz * dz), 1e-8f);
            float k = cwsel * __builtin_amdgcn_rcpf(len);
            atomicAdd(out_x + dn * 3,     k * dx);
            atomicAdd(out_x + dn * 3 + 1, k * dy);
            atomicAdd(out_x + dn * 3 + 2, k * dz);
        }
    }

    // ---- GEMM1-node ----
    f32x4 accN[2][8];
    #pragma unroll
    for (int a = 0; a < 2; ++a)
        #pragma unroll
        for (int b = 0; b < 8; ++b) accN[a][b] = zero;
    {
        const unsigned short* wsrc = ws;           // node_w1^T
        #pragma unroll
        for (int half = 0; half < 2; ++half) {
            #pragma unroll
            for (int kc = 0; kc < 5; ++kc) {
                #pragma unroll
                for (int nt = 0; nt < 4; ++nt) {
                    short8 b = *(const short8*)(wsrc + half * 10240 + nt * 2560
                                                + kc * 32 + wvoff);
                    const int nn = half * 4 + nt;
                    accN[0][nn] = __builtin_amdgcn_mfma_f32_16x16x32_bf16(aA[kc], b, accN[0][nn], 0, 0, 0);
                    accN[1][nn] = __builtin_amdgcn_mfma_f32_16x16x32_bf16(aB[kc], b, accN[1][nn], 0, 0, 0);
                }
            }
        }
    }

    // ---- hidden = silu(accN + b1) -> bf16, overwrite OWN rows of mi ----
    // no barrier needed: rows [w*32, w*32+32) are written and read only by wave w,
    // and the compiler orders same-wave ds_write -> ds_read via lgkmcnt.
    #pragma unroll
    for (int mt = 0; mt < 2; ++mt) {
        const int rowb = (w * 32 + mt * 16 + quad * 4) * MIS;
        #pragma unroll
        for (int nt = 0; nt < 8; ++nt) {
            int col = nt * 16 + ln;
            float b1v = node_b1[col];
            #pragma unroll
            for (int r = 0; r < 4; ++r)
                mi[rowb + r * MIS + col] = f2bf(silu_f(accN[mt][nt][r] + b1v));
        }
    }

    // ---- GEMM2-node: [128,128] @ [128,64] ----
    f32x4 acc2[2][4];
    #pragma unroll
    for (int a = 0; a < 2; ++a)
        #pragma unroll
        for (int b = 0; b < 4; ++b) acc2[a][b] = zero;
    const unsigned short* nw2T = ws + 40960;
    #pragma unroll
    for (int kc = 0; kc < 4; ++kc) {
        short8 a0 = *(const short8*)&mi[arow0 + kc * 32 + koff];
        short8 a1 = *(const short8*)&mi[arow1 + kc * 32 + koff];
        #pragma unroll
        for (int nt = 0; nt < 4; ++nt) {
            short8 b = *(const short8*)(nw2T + (nt * 16 + ln) * 128 + kc * 32 + koff);
            acc2[0][nt] = __builtin_amdgcn_mfma_f32_16x16x32_bf16(a0, b, acc2[0][nt], 0, 0, 0);
            acc2[1][nt] = __builtin_amdgcn_mfma_f32_16x16x32_bf16(a1, b, acc2[1][nt], 0, 0, 0);
        }
    }
    // ---- node scatter: out_h[dst] += m + b2 ----
    #pragma unroll
    for (int mt = 0; mt < 2; ++mt) {
        #pragma unroll
        for (int r = 0; r < 4; ++r) {
            int lrow = w * 32 + mt * 16 + quad * 4 + r;
            int dn = dstS[lrow];
            float* outrow = out_h + (size_t)dn * 64;
            #pragma unroll
            for (int nt = 0; nt < 4; ++nt) {
                int col = nt * 16 + ln;
                atomicAdd(outrow + col, acc2[mt][nt][r] + node_b2[col]);
            }
        }
    }
}

extern "C" void kernel_launch(void* const* d_in, const int* in_sizes, int n_in,
                              void* d_out, int out_size, void* d_ws, size_t ws_size,
                              hipStream_t stream) {
    const float* h    = (const float*)d_in[0];
    const float* x    = (const float*)d_in[1];
    const int*   eidx = (const int*)d_in[2];
    const float* edist= (const float*)d_in[3];
    const float* nw1  = (const float*)d_in[4];
    const float* nb1  = (const float*)d_in[5];
    const float* nw2  = (const float*)d_in[6];
    const float* nb2  = (const float*)d_in[7];
    const float* cw1  = (const float*)d_in[8];
    const float* cb1  = (const float*)d_in[9];
    const float* cw2  = (const float*)d_in[10];
    const float* ew1  = (const float*)d_in[11];
    const float* eb1  = (const float*)d_in[12];
    const float* ew2  = (const float*)d_in[13];
    const float* eb2  = (const float*)d_in[14];
    float* out = (float*)d_out;
    unsigned short* ws = (unsigned short*)d_ws;

    prep_kernel<<<192, 256, 0, stream>>>(nw1, cw1, nw2, ws);
    init_out<<<3272, 256, 0, stream>>>((const float4*)h, (const float4*)x, (float4*)out);
    egnn_edge_kernel<<<NE / BE, 256, 0, stream>>>(h, x, eidx, edist,
                                                  nb1, nb2, cb1, cw2,
                                                  ew1, eb1, ew2, eb2,
                                                  ws, out, out + 3200000);
}

// Round 5
// 742.336 us; speedup vs baseline: 1.9672x; 1.1162x over previous
//
#include <hip/hip_runtime.h>
#include <hip/hip_bf16.h>
#include <stdint.h>

#define NN 50000
#define NE 1600000
#define BE 128

typedef __attribute__((ext_vector_type(8))) short short8;
typedef __attribute__((ext_vector_type(4))) float f32x4;

__device__ __forceinline__ unsigned short f2bf(float f) {
    unsigned int u = __float_as_uint(f);
    u += 0x7fff + ((u >> 16) & 1);   // round-nearest-even
    return (unsigned short)(u >> 16);
}

// packed 2x f32 -> 2x bf16 (v_cvt_pk_bf16_f32 on gfx950)
__device__ __forceinline__ unsigned int pk2bf(float lo, float hi) {
    __hip_bfloat162 b = __float22bfloat162_rn(float2{lo, hi});
    return *(unsigned int*)&b;
}

// silu via fast rcp (v_rcp_f32) instead of precise divide
__device__ __forceinline__ float silu_f(float v) {
    return v * __builtin_amdgcn_rcpf(1.0f + __expf(-v));
}

// ws layout (bytes):
// [0, 98304)            bf16 weights: node_w1^T [128][160] | coord_w1^T [128][160] | node_w2^T [64][128]
// [98304, 100352)       ew2^T bf16 [32 out][32 k]
// [100352, 6500352)     h_bf16 [50000][64]          (optional, ws_size-gated)
// [6500352, 7300352)    x4 float4 [50000]           (optional, ws_size-gated)
#define WS_EW2T_US   49152          // ushort offset of ew2T
#define WS_HB_B      100352
#define WS_XP_B      6500352
#define WS_HB_NEED   6500352
#define WS_XP_NEED   7300352

__global__ void prep_kernel(const float* __restrict__ nw1,
                            const float* __restrict__ cw1,
                            const float* __restrict__ nw2,
                            const float* __restrict__ ew2,
                            unsigned short* __restrict__ ws) {
    int i = blockIdx.x * 256 + threadIdx.x;
    if (i < 20480) {
        int n = i / 160, k = i % 160;
        ws[i] = f2bf(nw1[k * 128 + n]);
    } else if (i < 40960) {
        int j = i - 20480; int n = j / 160, k = j % 160;
        ws[i] = f2bf(cw1[k * 128 + n]);
    } else if (i < 49152) {
        int j = i - 40960; int o = j / 128, k = j % 128;
        ws[i] = f2bf(nw2[k * 64 + o]);
    } else if (i < 50176) {
        int j = i - 49152; int jo = j >> 5, k = j & 31;
        ws[i] = f2bf(ew2[k * 32 + jo]);
    }
}

// h fp32 -> bf16 copy (streaming)
__global__ void hcvt_kernel(const float4* __restrict__ h4,
                            unsigned short* __restrict__ hb) {
    int i = blockIdx.x * 256 + threadIdx.x;   // 800000 float4s
    if (i < 800000) {
        float4 v = h4[i];
        uint2 u;
        u.x = pk2bf(v.x, v.y);
        u.y = pk2bf(v.z, v.w);
        *(uint2*)&hb[i * 4] = u;
    }
}

// x [NN][3] -> padded float4 copy
__global__ void xpack_kernel(const float* __restrict__ x,
                             float4* __restrict__ xp) {
    int n = blockIdx.x * 256 + threadIdx.x;
    if (n < NN) {
        xp[n] = float4{x[n * 3], x[n * 3 + 1], x[n * 3 + 2], 0.f};
    }
}

// out[0:3.2M] = h, out[3.2M:3.35M] = x   (both div by 4)
__global__ void init_out(const float4* __restrict__ h4,
                         const float4* __restrict__ x4,
                         float4* __restrict__ out4) {
    int i = blockIdx.x * 256 + threadIdx.x;
    if (i < 800000)       out4[i] = h4[i];
    else if (i < 837500)  out4[i] = x4[i - 800000];
}

#define MIS 168   // m_input row stride (ushorts); 336B = 21*16B -> aligned + 2-way-free banks

__global__ __launch_bounds__(256, 3)
void egnn_edge_kernel(const float* __restrict__ h,
                      const unsigned short* __restrict__ hb,   // bf16 h copy (or null)
                      const float* __restrict__ x,
                      const float4* __restrict__ xp,           // packed x copy (or null)
                      const int* __restrict__ eidx,
                      const float* __restrict__ edist,
                      const float* __restrict__ node_b1,
                      const float* __restrict__ node_b2,
                      const float* __restrict__ coord_b1,
                      const float* __restrict__ coord_w2,
                      const float* __restrict__ ew1,
                      const float* __restrict__ eb1,
                      const float* __restrict__ eb2,
                      const unsigned short* __restrict__ ws,
                      float* __restrict__ out_h,
                      float* __restrict__ out_x) {
    // LDS: 128*168*2 + 1KB = 44032 B -> 3 blocks/CU (12 waves/CU)
    __shared__ unsigned short mi[BE * MIS];     // m_input tile, later hidden tile
    __shared__ int srcS[BE];
    __shared__ int dstS[BE];

    const int tid  = threadIdx.x;
    const int w    = tid >> 6;      // wave 0..3, owns edge rows [w*32, w*32+32)
    const int lane = tid & 63;
    const int ln   = lane & 15;
    const int quad = lane >> 4;
    const int e0   = blockIdx.x * BE;

    // ---- preload edge indices once (coalesced) ----
    if (tid < BE)      srcS[tid]       = eidx[e0 + tid];
    else               dstS[tid - BE]  = eidx[NE + e0 + tid - BE];
    __syncthreads();

    // ---- stage m_input cols 0..127: gather h[src], h[dst] as bf16 ----
    if (hb) {
        const uint2* hb2 = (const uint2*)hb;    // 4 bf16 per uint2, 16 per row
        const int g = tid >> 4, l16 = tid & 15;
        #pragma unroll
        for (int it = 0; it < 16; ++it) {
            int row = it * 16 + g;
            int e = row & 127;
            int node = (row < 128) ? srcS[e] : dstS[e];
            int cbase = (row < 128) ? 0 : 64;
            *(uint2*)&mi[e * MIS + cbase + l16 * 4] = hb2[node * 16 + l16];
        }
    } else {
        const float4* h4 = (const float4*)h;
        const int g = tid >> 4, l16 = tid & 15;
        #pragma unroll
        for (int it = 0; it < 16; ++it) {
            int row = it * 16 + g;
            int e = row & 127;
            int node = (row < 128) ? srcS[e] : dstS[e];
            int cbase = (row < 128) ? 0 : 64;
            float4 v = h4[node * 16 + l16];
            uint2 u;
            u.x = pk2bf(v.x, v.y);
            u.y = pk2bf(v.z, v.w);
            *(uint2*)&mi[e * MIS + cbase + l16 * 4] = u;
        }
    }
    // ---- stage cols 128..159 with tmat: t[e][k] = silu(d*ew1[k]+eb1[k]) ----
    // thread (e = tid>>1, half = tid&1) covers k = half*16..+16; own-wave rows.
    {
        int e = tid >> 1, half = tid & 1;
        float d = edist[e0 + e];
        float t[16];
        #pragma unroll
        for (int j = 0; j < 16; ++j) {
            int k = half * 16 + j;
            t[j] = silu_f(d * ew1[k] + eb1[k]);
        }
        uint4 u0, u1;
        u0.x = pk2bf(t[0], t[1]);   u0.y = pk2bf(t[2], t[3]);
        u0.z = pk2bf(t[4], t[5]);   u0.w = pk2bf(t[6], t[7]);
        u1.x = pk2bf(t[8], t[9]);   u1.y = pk2bf(t[10], t[11]);
        u1.z = pk2bf(t[12], t[13]); u1.w = pk2bf(t[14], t[15]);
        *(uint4*)&mi[e * MIS + 128 + half * 16]     = u0;
        *(uint4*)&mi[e * MIS + 128 + half * 16 + 8] = u1;
    }

    __syncthreads();   // staging complete; from here each wave touches only its own rows

    const int arow0 = (w * 32 + ln) * MIS;
    const int arow1 = (w * 32 + 16 + ln) * MIS;
    const int koff  = quad * 8;
    const f32x4 zero = {0.f, 0.f, 0.f, 0.f};

    // ---- edge_attr = tmat @ ew2 + eb2, via MFMA, in place (cols 128..159) ----
    // Safe in-wave in-place: all ds_reads issue before ds_writes in program order.
    {
        const unsigned short* e2T = ws + WS_EW2T_US;
        short8 ta0 = *(const short8*)&mi[arow0 + 128 + koff];
        short8 ta1 = *(const short8*)&mi[arow1 + 128 + koff];
        f32x4 ea[2][2];
        ea[0][0] = zero; ea[0][1] = zero; ea[1][0] = zero; ea[1][1] = zero;
        #pragma unroll
        for (int nt = 0; nt < 2; ++nt) {
            short8 b = *(const short8*)(e2T + (nt * 16 + ln) * 32 + koff);
            ea[0][nt] = __builtin_amdgcn_mfma_f32_16x16x32_bf16(ta0, b, ea[0][nt], 0, 0, 0);
            ea[1][nt] = __builtin_amdgcn_mfma_f32_16x16x32_bf16(ta1, b, ea[1][nt], 0, 0, 0);
        }
        #pragma unroll
        for (int nt = 0; nt < 2; ++nt) {
            int col = nt * 16 + ln;
            float bv = eb2[col];
            #pragma unroll
            for (int rt = 0; rt < 2; ++rt) {
                #pragma unroll
                for (int r = 0; r < 4; ++r)
                    mi[(w * 32 + rt * 16 + quad * 4 + r) * MIS + 128 + col] =
                        f2bf(ea[rt][nt][r] + bv);
            }
        }
    }

    // ---- A fragments: load once, reuse for both GEMM1 phases ----
    short8 aA[5], aB[5];
    #pragma unroll
    for (int kc = 0; kc < 5; ++kc) {
        aA[kc] = *(const short8*)&mi[arow0 + kc * 32 + koff];
        aB[kc] = *(const short8*)&mi[arow1 + kc * 32 + koff];
    }

    const int wvoff = ln * 160 + koff;   // per-lane B-row offset (ushorts)

    // ---- GEMM1-coord: [128,160] @ [160,128], B straight from global (L1/L2-hot) ----
    f32x4 accC[2][8];
    #pragma unroll
    for (int a = 0; a < 2; ++a)
        #pragma unroll
        for (int b = 0; b < 8; ++b) accC[a][b] = zero;
    {
        const unsigned short* wsrc = ws + 20480;   // coord_w1^T
        #pragma unroll
        for (int half = 0; half < 2; ++half) {
            #pragma unroll
            for (int kc = 0; kc < 5; ++kc) {
                #pragma unroll
                for (int nt = 0; nt < 4; ++nt) {
                    short8 b = *(const short8*)(wsrc + half * 10240 + nt * 2560
                                                + kc * 32 + wvoff);
                    const int nn = half * 4 + nt;
                    accC[0][nn] = __builtin_amdgcn_mfma_f32_16x16x32_bf16(aA[kc], b, accC[0][nn], 0, 0, 0);
                    accC[1][nn] = __builtin_amdgcn_mfma_f32_16x16x32_bf16(aB[kc], b, accC[1][nn], 0, 0, 0);
                }
            }
        }
    }

    // ---- coord epilogue: cw[e] = silu(accC + b1c) . w2c, then x scatter ----
    {
        float cw[2][4];
        #pragma unroll
        for (int mt = 0; mt < 2; ++mt)
            #pragma unroll
            for (int r = 0; r < 4; ++r) cw[mt][r] = 0.f;
        #pragma unroll
        for (int nt = 0; nt < 8; ++nt) {
            int col = nt * 16 + ln;
            float b1v = coord_b1[col];
            float w2v = coord_w2[col];
            #pragma unroll
            for (int mt = 0; mt < 2; ++mt)
                #pragma unroll
                for (int r = 0; r < 4; ++r)
                    cw[mt][r] += silu_f(accC[mt][nt][r] + b1v) * w2v;
        }
        #pragma unroll
        for (int off = 1; off < 16; off <<= 1) {
            #pragma unroll
            for (int mt = 0; mt < 2; ++mt)
                #pragma unroll
                for (int r = 0; r < 4; ++r)
                    cw[mt][r] += __shfl_xor(cw[mt][r], off, 64);
        }
        if (ln < 8) {
            const int smt = ln >> 2, sr = ln & 3;
            float cwsel = 0.f;
            #pragma unroll
            for (int mt = 0; mt < 2; ++mt)
                #pragma unroll
                for (int r = 0; r < 4; ++r)
                    cwsel = (mt == smt && r == sr) ? cw[mt][r] : cwsel;
            int lrow = w * 32 + smt * 16 + quad * 4 + sr;
            int s = srcS[lrow], dn = dstS[lrow];
            float dx, dy, dz;
            if (xp) {
                float4 xs = xp[s], xd = xp[dn];
                dx = xs.x - xd.x; dy = xs.y - xd.y; dz = xs.z - xd.z;
            } else {
                dx = x[s * 3]     - x[dn * 3];
                dy = x[s * 3 + 1] - x[dn * 3 + 1];
                dz = x[s * 3 + 2] - x[dn * 3 + 2];
            }
            float len = fmaxf(sqrtf(dx * dx + dy * dy + dz * dz), 1e-8f);
            float k = cwsel * __builtin_amdgcn_rcpf(len);
            atomicAdd(out_x + dn * 3,     k * dx);
            atomicAdd(out_x + dn * 3 + 1, k * dy);
            atomicAdd(out_x + dn * 3 + 2, k * dz);
        }
    }

    // ---- GEMM1-node ----
    f32x4 accN[2][8];
    #pragma unroll
    for (int a = 0; a < 2; ++a)
        #pragma unroll
        for (int b = 0; b < 8; ++b) accN[a][b] = zero;
    {
        const unsigned short* wsrc = ws;           // node_w1^T
        #pragma unroll
        for (int half = 0; half < 2; ++half) {
            #pragma unroll
            for (int kc = 0; kc < 5; ++kc) {
                #pragma unroll
                for (int nt = 0; nt < 4; ++nt) {
                    short8 b = *(const short8*)(wsrc + half * 10240 + nt * 2560
                                                + kc * 32 + wvoff);
                    const int nn = half * 4 + nt;
                    accN[0][nn] = __builtin_amdgcn_mfma_f32_16x16x32_bf16(aA[kc], b, accN[0][nn], 0, 0, 0);
                    accN[1][nn] = __builtin_amdgcn_mfma_f32_16x16x32_bf16(aB[kc], b, accN[1][nn], 0, 0, 0);
                }
            }
        }
    }

    // ---- hidden = silu(accN + b1) -> bf16, overwrite OWN rows of mi ----
    #pragma unroll
    for (int mt = 0; mt < 2; ++mt) {
        const int rowb = (w * 32 + mt * 16 + quad * 4) * MIS;
        #pragma unroll
        for (int nt = 0; nt < 8; ++nt) {
            int col = nt * 16 + ln;
            float b1v = node_b1[col];
            #pragma unroll
            for (int r = 0; r < 4; ++r)
                mi[rowb + r * MIS + col] = f2bf(silu_f(accN[mt][nt][r] + b1v));
        }
    }

    // ---- GEMM2-node: [128,128] @ [128,64] ----
    f32x4 acc2[2][4];
    #pragma unroll
    for (int a = 0; a < 2; ++a)
        #pragma unroll
        for (int b = 0; b < 4; ++b) acc2[a][b] = zero;
    const unsigned short* nw2T = ws + 40960;
    #pragma unroll
    for (int kc = 0; kc < 4; ++kc) {
        short8 a0 = *(const short8*)&mi[arow0 + kc * 32 + koff];
        short8 a1 = *(const short8*)&mi[arow1 + kc * 32 + koff];
        #pragma unroll
        for (int nt = 0; nt < 4; ++nt) {
            short8 b = *(const short8*)(nw2T + (nt * 16 + ln) * 128 + kc * 32 + koff);
            acc2[0][nt] = __builtin_amdgcn_mfma_f32_16x16x32_bf16(a0, b, acc2[0][nt], 0, 0, 0);
            acc2[1][nt] = __builtin_amdgcn_mfma_f32_16x16x32_bf16(a1, b, acc2[1][nt], 0, 0, 0);
        }
    }
    // ---- node scatter: out_h[dst] += m + b2 ----
    #pragma unroll
    for (int mt = 0; mt < 2; ++mt) {
        #pragma unroll
        for (int r = 0; r < 4; ++r) {
            int lrow = w * 32 + mt * 16 + quad * 4 + r;
            int dn = dstS[lrow];
            float* outrow = out_h + (size_t)dn * 64;
            #pragma unroll
            for (int nt = 0; nt < 4; ++nt) {
                int col = nt * 16 + ln;
                atomicAdd(outrow + col, acc2[mt][nt][r] + node_b2[col]);
            }
        }
    }
}

extern "C" void kernel_launch(void* const* d_in, const int* in_sizes, int n_in,
                              void* d_out, int out_size, void* d_ws, size_t ws_size,
                              hipStream_t stream) {
    const float* h    = (const float*)d_in[0];
    const float* x    = (const float*)d_in[1];
    const int*   eidx = (const int*)d_in[2];
    const float* edist= (const float*)d_in[3];
    const float* nw1  = (const float*)d_in[4];
    const float* nb1  = (const float*)d_in[5];
    const float* nw2  = (const float*)d_in[6];
    const float* nb2  = (const float*)d_in[7];
    const float* cw1  = (const float*)d_in[8];
    const float* cb1  = (const float*)d_in[9];
    const float* cw2  = (const float*)d_in[10];
    const float* ew1  = (const float*)d_in[11];
    const float* eb1  = (const float*)d_in[12];
    const float* ew2  = (const float*)d_in[13];
    const float* eb2  = (const float*)d_in[14];
    float* out = (float*)d_out;
    unsigned short* ws = (unsigned short*)d_ws;

    prep_kernel<<<196, 256, 0, stream>>>(nw1, cw1, nw2, ew2, ws);
    init_out<<<3272, 256, 0, stream>>>((const float4*)h, (const float4*)x, (float4*)out);

    unsigned short* hb = nullptr;
    float4* xp = nullptr;
    if (ws_size >= (size_t)WS_HB_NEED) {
        hb = (unsigned short*)((char*)d_ws + WS_HB_B);
        hcvt_kernel<<<3125, 256, 0, stream>>>((const float4*)h, hb);
    }
    if (ws_size >= (size_t)WS_XP_NEED) {
        xp = (float4*)((char*)d_ws + WS_XP_B);
        xpack_kernel<<<196, 256, 0, stream>>>(x, xp);
    }

    egnn_edge_kernel<<<NE / BE, 256, 0, stream>>>(h, hb, x, xp, eidx, edist,
                                                  nb1, nb2, cb1, cw2,
                                                  ew1, eb1, eb2,
                                                  ws, out, out + 3200000);
}